// Round 15
// baseline (167.669 us; speedup 1.0000x reference)
//
#include <hip/hip_runtime.h>
#include <math.h>

#define HIDDEN 64
#define TARGET 10
#define BKSH 9            // coarse bucket = 512 dst nodes
#define NBKMAX 256        // max coarse buckets (N <= 131072)

static __device__ __forceinline__ unsigned short f2bf(float f) {
    unsigned int u = __float_as_uint(f);
    u = (u + 0x7fffu + ((u >> 16) & 1u)) >> 16;   // RNE
    return (unsigned short)u;
}
static __device__ __forceinline__ float bf2f(unsigned short v) {
    return __uint_as_float((unsigned int)v << 16);
}

// ---------------------------------------------------------------------------
// K2: per-node, LDS-tiled register-blocked matmul (validated r2-r14).
//  x = relu(emb_act[act]+emb_loc[loc]); h = x @ W_gat (bf16 out)
//  a_src/a_dst folded in as reduction of the accumulator tile.
// ---------------------------------------------------------------------------
__global__ __launch_bounds__(256) void k_nodes(
        const int* __restrict__ act, const int* __restrict__ loc,
        const float* __restrict__ emb_act,
        const float* __restrict__ emb_loc,
        const float* __restrict__ W_gat,
        const float* __restrict__ att_src,
        const float* __restrict__ att_dst,
        unsigned short* __restrict__ hb,
        float* __restrict__ a_src, float* __restrict__ a_dst,
        int N) {
    __shared__ float xs[64][68];
    __shared__ float Wl[64][68];
    __shared__ int acts[64], locs[64];
    int tid = threadIdx.x;
    int base = blockIdx.x * 64;

    for (int i = tid; i < 4096; i += 256) Wl[i >> 6][i & 63] = W_gat[i];
    if (tid < 64) {
        int n = base + tid;
        acts[tid] = (n < N) ? act[n] : 0;
        locs[tid] = (n < N) ? loc[n] : 0;
    }
    __syncthreads();

    for (int i = tid; i < 1024; i += 256) {
        int r = i >> 4, k4 = i & 15;
        int n = base + r;
        float4 v = make_float4(0.f, 0.f, 0.f, 0.f);
        if (n < N) {
            float4 a = ((const float4*)emb_act)[acts[r] * 16 + k4];
            float4 b = ((const float4*)emb_loc)[locs[r] * 16 + k4];
            v.x = fmaxf(a.x + b.x, 0.f);
            v.y = fmaxf(a.y + b.y, 0.f);
            v.z = fmaxf(a.z + b.z, 0.f);
            v.w = fmaxf(a.w + b.w, 0.f);
        }
        *(float4*)&xs[r][k4 * 4] = v;
    }
    __syncthreads();

    int tx = tid & 15, ty = tid >> 4;
    float acc[4][4];
#pragma unroll
    for (int i = 0; i < 4; i++)
#pragma unroll
        for (int j = 0; j < 4; j++) acc[i][j] = 0.f;

#pragma unroll 4
    for (int k4 = 0; k4 < 16; k4++) {
        float4 xv[4], wv[4];
#pragma unroll
        for (int i = 0; i < 4; i++) xv[i] = *(const float4*)&xs[ty * 4 + i][k4 * 4];
#pragma unroll
        for (int kk = 0; kk < 4; kk++) wv[kk] = *(const float4*)&Wl[k4 * 4 + kk][tx * 4];
#pragma unroll
        for (int i = 0; i < 4; i++) {
            float xk0 = xv[i].x, xk1 = xv[i].y, xk2 = xv[i].z, xk3 = xv[i].w;
            acc[i][0] += xk0 * wv[0].x + xk1 * wv[1].x + xk2 * wv[2].x + xk3 * wv[3].x;
            acc[i][1] += xk0 * wv[0].y + xk1 * wv[1].y + xk2 * wv[2].y + xk3 * wv[3].y;
            acc[i][2] += xk0 * wv[0].z + xk1 * wv[1].z + xk2 * wv[2].z + xk3 * wv[3].z;
            acc[i][3] += xk0 * wv[0].w + xk1 * wv[1].w + xk2 * wv[2].w + xk3 * wv[3].w;
        }
    }

#pragma unroll
    for (int i = 0; i < 4; i++) {
        int n = base + ty * 4 + i;
        if (n < N) {
            ushort4 hv;
            hv.x = f2bf(acc[i][0]); hv.y = f2bf(acc[i][1]);
            hv.z = f2bf(acc[i][2]); hv.w = f2bf(acc[i][3]);
            *(ushort4*)&hb[(size_t)n * 64 + tx * 4] = hv;
        }
    }

    float4 as4 = ((const float4*)att_src)[tx];
    float4 ad4 = ((const float4*)att_dst)[tx];
    float ps[4], pd[4];
#pragma unroll
    for (int i = 0; i < 4; i++) {
        ps[i] = acc[i][0] * as4.x + acc[i][1] * as4.y + acc[i][2] * as4.z + acc[i][3] * as4.w;
        pd[i] = acc[i][0] * ad4.x + acc[i][1] * ad4.y + acc[i][2] * ad4.z + acc[i][3] * ad4.w;
    }
#pragma unroll
    for (int off = 1; off < 16; off <<= 1) {
#pragma unroll
        for (int i = 0; i < 4; i++) {
            ps[i] += __shfl_xor(ps[i], off, 64);
            pd[i] += __shfl_xor(pd[i], off, 64);
        }
    }
    if (tx == 0) {
#pragma unroll
        for (int i = 0; i < 4; i++) {
            int n = base + ty * 4 + i;
            if (n < N) { a_src[n] = ps[i]; a_dst[n] = pd[i]; }
        }
    }
}

// ---------------------------------------------------------------------------
// K3a: binned scatter pass A, fixed-capacity slabs, 4096 edges/block
// (halved reservation rounds vs r14). Inlined edge-table compute.
// Record: p.x = src | (d&511)<<20 ; p.y = exp(leaky_relu(alpha)) bits.
// ---------------------------------------------------------------------------
__global__ __launch_bounds__(256) void k_binA(
        const int* __restrict__ src, const int* __restrict__ dst,
        const int* __restrict__ travel,
        const float* __restrict__ dur,
        const float* __restrict__ tst,
        const float* __restrict__ tet,
        const float* __restrict__ a_src,
        const float* __restrict__ a_dst,
        const float* __restrict__ W_edge,
        const float* __restrict__ att_edge,
        const float* __restrict__ emb_travel,
        int* __restrict__ bcur,
        int2* __restrict__ epk, int E, int CAP) {
    __shared__ float we_s[67];
    __shared__ float ttbl[8];
    __shared__ float c012[3];
    __shared__ int cnt[NBKMAX];
    __shared__ int gb[NBKMAX];
    int tid = threadIdx.x;
    if (tid < 67) {
        float s = 0.f;
        for (int j = 0; j < 64; j++) s += W_edge[tid * 64 + j] * att_edge[j];
        we_s[tid] = s;
    }
    if (tid < NBKMAX) cnt[tid] = 0;
    __syncthreads();
    if (tid < 8) {
        float s = 0.f;
        for (int k = 0; k < 64; k++) s += emb_travel[tid * 64 + k] * we_s[k];
        ttbl[tid] = s;
    }
    if (tid == 64) { c012[0] = we_s[64]; c012[1] = we_s[65]; c012[2] = we_s[66]; }
    __syncthreads();
    float c0 = c012[0], c1 = c012[1], c2 = c012[2];

    int base = blockIdx.x * 4096 + tid;
    int rx[16], bks[16];
    float rv[16];
    bool ok[16];
#pragma unroll
    for (int j = 0; j < 16; j++) {
        int e = base + j * 256;
        ok[j] = e < E;
        if (ok[j]) {
            int s = src[e], d = dst[e];
            float al = a_src[s] + a_dst[d] + ttbl[travel[e]]
                     + c0 * dur[e] + c1 * tst[e] + c2 * tet[e];
            al = al > 0.f ? al : 0.2f * al;
            rv[j] = __expf(al);
            rx[j] = s | ((d & 511) << 20);
            bks[j] = d >> BKSH;
            atomicAdd(&cnt[bks[j]], 1);
        }
    }
    __syncthreads();
    if (tid < NBKMAX) {
        int c = cnt[tid];
        gb[tid] = c ? atomicAdd(&bcur[tid], c) : 0;
        cnt[tid] = 0;
    }
    __syncthreads();
#pragma unroll
    for (int j = 0; j < 16; j++) {
        if (ok[j]) {
            int slot = atomicAdd(&cnt[bks[j]], 1);
            int2 p;
            p.x = rx[j];
            p.y = __float_as_int(rv[j]);
            epk[(size_t)bks[j] * CAP + gb[bks[j]] + slot] = p;
        }
    }
}

// ---------------------------------------------------------------------------
// K3b: binned scatter pass B + LOCAL CSR (validated r13/r14). One block per
// 512-dst bucket: LDS hist -> wave-0 scan -> rowse[n]=(start,end) ->
// LDS-cursor sort into epk2 slab. All traffic L2-window-resident.
// ---------------------------------------------------------------------------
__global__ __launch_bounds__(256) void k_binB(
        const int2* __restrict__ epk,
        const int* __restrict__ bcur,
        int2* __restrict__ epk2,
        int2* __restrict__ rowse, int N, int CAP) {
    __shared__ int cnt[512];
    __shared__ int cur[512];
    int tid = threadIdx.x;
    int bk = blockIdx.x;
    int n0 = bk << BKSH;
    int cnt0 = bcur[bk];
    size_t base = (size_t)bk * CAP;

    for (int j = tid; j < 512; j += 256) cnt[j] = 0;
    __syncthreads();
    const int* epx = (const int*)epk;
    for (int i = tid; i < cnt0; i += 256)
        atomicAdd(&cnt[(epx[(base + i) * 2] >> 20) & 511], 1);
    __syncthreads();
    if (tid < 64) {
        int carry = 0;
#pragma unroll
        for (int c = 0; c < 8; c++) {
            int idx = c * 64 + tid;
            int v = cnt[idx];
            int s = v;
#pragma unroll
            for (int off = 1; off < 64; off <<= 1) {
                int t = __shfl_up(s, off, 64);
                if (tid >= off) s += t;
            }
            int excl = carry + s - v;
            cur[idx] = excl;
            int n = n0 + idx;
            if (n < N) rowse[n] = make_int2((int)base + excl, (int)base + excl + v);
            carry += __shfl(s, 63, 64);
        }
    }
    __syncthreads();
    for (int i = tid; i < cnt0; i += 256) {
        int2 p = epk[base + i];
        int dl = (p.x >> 20) & 511;
        int pos = atomicAdd(&cur[dl], 1);
        epk2[base + pos] = p;
    }
}

// ---------------------------------------------------------------------------
// K3f: atomic-free gather, contiguous node chunks per wave, in-register
// pooled accumulation with graph-boundary flush. NEW: 16 edges in flight
// (2 independent record->h dependency chains per group; invalid slots
// masked by ev*0 with address clamped to a valid record).
// ---------------------------------------------------------------------------
__global__ __launch_bounds__(256) void k_gather(
        const int2* __restrict__ epk,
        const int2* __restrict__ rowse,
        const uint4* __restrict__ hbq,
        const float4* __restrict__ bg4,
        const int* __restrict__ batch,
        float* __restrict__ pooled_sums, int N) {
    int lane = threadIdx.x & 63;
    int wid = (blockIdx.x * blockDim.x + threadIdx.x) >> 6;
    int nw = (gridDim.x * blockDim.x) >> 6;
    int chunk = (N + nw - 1) / nw;
    int n0 = wid * chunk;
    if (n0 >= N) return;
    int n1 = n0 + chunk;
    if (n1 > N) n1 = N;
    int grp = lane >> 3;   // 8 edge groups
    int sub = lane & 7;    // 16B slice of the h row
    float4 b0 = bg4[sub * 2], b1 = bg4[sub * 2 + 1];
    int curg = -1;
    float p0 = 0.f, p1 = 0.f, p2 = 0.f, p3 = 0.f;
    float p4 = 0.f, p5 = 0.f, p6 = 0.f, p7 = 0.f;
    for (int n = n0; n < n1; n++) {
        int g = batch[n];
        if (g != curg) {
            if (curg >= 0 && grp == 0) {
                float* ps = &pooled_sums[(size_t)curg * 64 + sub * 8];
                unsafeAtomicAdd(ps + 0, p0);
                unsafeAtomicAdd(ps + 1, p1);
                unsafeAtomicAdd(ps + 2, p2);
                unsafeAtomicAdd(ps + 3, p3);
                unsafeAtomicAdd(ps + 4, p4);
                unsafeAtomicAdd(ps + 5, p5);
                unsafeAtomicAdd(ps + 6, p6);
                unsafeAtomicAdd(ps + 7, p7);
            }
            p0 = p1 = p2 = p3 = p4 = p5 = p6 = p7 = 0.f;
            curg = g;
        }
        int2 se = rowse[n];
        float a0 = 0.f, a1 = 0.f, a2 = 0.f, a3 = 0.f;
        float a4 = 0.f, a5 = 0.f, a6 = 0.f, a7 = 0.f, dv = 0.f;
        int lastE = se.y - 1;
        for (int e0 = se.x; e0 < se.y; e0 += 16) {
            int ea = e0 + grp;
            int eb = ea + 8;
            float ma = ea <= lastE ? 1.f : 0.f;
            float mb = eb <= lastE ? 1.f : 0.f;
            ea = ea <= lastE ? ea : lastE;
            eb = eb <= lastE ? eb : lastE;
            int2 pa = epk[ea];
            int2 pb = epk[eb];
            float eva = __int_as_float(pa.y) * ma;
            float evb = __int_as_float(pb.y) * mb;
            uint4 hua = hbq[(size_t)(pa.x & 0xFFFFF) * 8 + sub];
            uint4 hub = hbq[(size_t)(pb.x & 0xFFFFF) * 8 + sub];
            a0 += eva * bf2f((unsigned short)(hua.x));
            a1 += eva * bf2f((unsigned short)(hua.x >> 16));
            a2 += eva * bf2f((unsigned short)(hua.y));
            a3 += eva * bf2f((unsigned short)(hua.y >> 16));
            a4 += eva * bf2f((unsigned short)(hua.z));
            a5 += eva * bf2f((unsigned short)(hua.z >> 16));
            a6 += eva * bf2f((unsigned short)(hua.w));
            a7 += eva * bf2f((unsigned short)(hua.w >> 16));
            a0 += evb * bf2f((unsigned short)(hub.x));
            a1 += evb * bf2f((unsigned short)(hub.x >> 16));
            a2 += evb * bf2f((unsigned short)(hub.y));
            a3 += evb * bf2f((unsigned short)(hub.y >> 16));
            a4 += evb * bf2f((unsigned short)(hub.z));
            a5 += evb * bf2f((unsigned short)(hub.z >> 16));
            a6 += evb * bf2f((unsigned short)(hub.w));
            a7 += evb * bf2f((unsigned short)(hub.w >> 16));
            dv += eva + evb;
        }
#pragma unroll
        for (int off = 8; off < 64; off <<= 1) {
            a0 += __shfl_xor(a0, off, 64);
            a1 += __shfl_xor(a1, off, 64);
            a2 += __shfl_xor(a2, off, 64);
            a3 += __shfl_xor(a3, off, 64);
            a4 += __shfl_xor(a4, off, 64);
            a5 += __shfl_xor(a5, off, 64);
            a6 += __shfl_xor(a6, off, 64);
            a7 += __shfl_xor(a7, off, 64);
            dv += __shfl_xor(dv, off, 64);
        }
        float dn = dv > 1e-16f ? dv : 1e-16f;
        float inv = 1.f / dn;
        p0 += fmaxf(a0 * inv + b0.x, 0.f);
        p1 += fmaxf(a1 * inv + b0.y, 0.f);
        p2 += fmaxf(a2 * inv + b0.z, 0.f);
        p3 += fmaxf(a3 * inv + b0.w, 0.f);
        p4 += fmaxf(a4 * inv + b1.x, 0.f);
        p5 += fmaxf(a5 * inv + b1.y, 0.f);
        p6 += fmaxf(a6 * inv + b1.z, 0.f);
        p7 += fmaxf(a7 * inv + b1.w, 0.f);
    }
    if (curg >= 0 && grp == 0) {
        float* ps = &pooled_sums[(size_t)curg * 64 + sub * 8];
        unsafeAtomicAdd(ps + 0, p0);
        unsafeAtomicAdd(ps + 1, p1);
        unsafeAtomicAdd(ps + 2, p2);
        unsafeAtomicAdd(ps + 3, p3);
        unsafeAtomicAdd(ps + 4, p4);
        unsafeAtomicAdd(ps + 5, p5);
        unsafeAtomicAdd(ps + 6, p6);
        unsafeAtomicAdd(ps + 7, p7);
    }
}

// ---------------------------------------------------------------------------
// K5: pooled = sums/cnt; logits = pooled @ W_fc + b_fc ; out = log_softmax.
// ---------------------------------------------------------------------------
__global__ void k_fc(const float* __restrict__ pooled_sums,
                     const int* __restrict__ batch, int N,
                     const float* __restrict__ W_fc,
                     const float* __restrict__ b_fc,
                     float* __restrict__ out, int G) {
    int lane = threadIdx.x & 63;
    int wid = (blockIdx.x * blockDim.x + threadIdx.x) >> 6;
    int nw = (gridDim.x * blockDim.x) >> 6;
    for (int g = wid; g < G; g += nw) {
        int lo = 0, hi = N;
        while (lo < hi) { int mid = (lo + hi) >> 1; if (batch[mid] < g) lo = mid + 1; else hi = mid; }
        int start = lo;
        hi = N;
        while (lo < hi) { int mid = (lo + hi) >> 1; if (batch[mid] < g + 1) lo = mid + 1; else hi = mid; }
        float cnt = (float)(lo - start);
        float inv = 1.f / (cnt > 1.f ? cnt : 1.f);
        float p = pooled_sums[(size_t)g * 64 + lane] * inv;
        float logit[TARGET];
#pragma unroll
        for (int t = 0; t < TARGET; t++) {
            float v = p * W_fc[lane * TARGET + t];
#pragma unroll
            for (int o = 32; o > 0; o >>= 1) v += __shfl_xor(v, o, 64);
            logit[t] = v + b_fc[t];
        }
        float m = logit[0];
#pragma unroll
        for (int t = 1; t < TARGET; t++) m = fmaxf(m, logit[t]);
        float se = 0.f;
#pragma unroll
        for (int t = 0; t < TARGET; t++) se += expf(logit[t] - m);
        float lse = m + logf(se);
#pragma unroll
        for (int t = 0; t < TARGET; t++)
            if (lane == t) out[g * TARGET + t] = logit[t] - lse;
    }
}

extern "C" void kernel_launch(void* const* d_in, const int* in_sizes, int n_in,
                              void* d_out, int out_size, void* d_ws, size_t ws_size,
                              hipStream_t stream) {
    const int*   act        = (const int*)d_in[0];
    const int*   loc        = (const int*)d_in[1];
    const int*   travel     = (const int*)d_in[2];
    const float* dur        = (const float*)d_in[3];
    const float* tst        = (const float*)d_in[4];
    const float* tet        = (const float*)d_in[5];
    const int*   ei         = (const int*)d_in[6];
    const int*   batch      = (const int*)d_in[7];
    const float* emb_act    = (const float*)d_in[8];
    const float* emb_loc    = (const float*)d_in[9];
    const float* emb_travel = (const float*)d_in[10];
    const float* W_gat      = (const float*)d_in[11];
    const float* att_src    = (const float*)d_in[12];
    const float* att_dst    = (const float*)d_in[13];
    const float* W_edge     = (const float*)d_in[14];
    const float* att_edge   = (const float*)d_in[15];
    const float* b_gat      = (const float*)d_in[16];
    const float* W_fc       = (const float*)d_in[17];
    const float* b_fc       = (const float*)d_in[18];
    float* out = (float*)d_out;

    int N = in_sizes[0];
    int E = in_sizes[2];
    int G = out_size / TARGET;
    int NBK = (N + 511) >> BKSH;                       // 196 coarse buckets
    int CAP = (((E + NBK - 1) / NBK) + 4096 + 15) & ~15;  // slab capacity

    float* ws = (float*)d_ws;
    size_t off = 0;
    unsigned short* hb = (unsigned short*)(ws + off); off += (size_t)N * 32;  // bf16 h, 16B-aligned
    float* a_src    = ws + off; off += N;
    float* a_dst    = ws + off; off += N;
    int*   bcur     = (int*)(ws + off); off += NBKMAX;
    float* pooled   = ws + off; off += (size_t)G * 64;   // adjacent to bcur: one memset
    if (off & 1) off++;                   // 8B-align int2 arrays
    int2*  rowse    = (int2*)(ws + off); off += (size_t)N * 2;
    int2*  epk      = (int2*)(ws + off); off += (size_t)NBK * CAP * 2;
    int2*  epk2     = (int2*)(ws + off); off += (size_t)NBK * CAP * 2;

    hipMemsetAsync(bcur, 0, (NBKMAX + (size_t)G * 64) * sizeof(float), stream);

    k_nodes<<<(N + 63) / 64, 256, 0, stream>>>(act, loc, emb_act, emb_loc, W_gat,
                                               att_src, att_dst, hb, a_src, a_dst, N);
    k_binA<<<(E + 4095) / 4096, 256, 0, stream>>>(ei, ei + E, travel, dur, tst, tet,
                                                  a_src, a_dst, W_edge, att_edge,
                                                  emb_travel, bcur, epk, E, CAP);
    k_binB<<<NBK, 256, 0, stream>>>(epk, bcur, epk2, rowse, N, CAP);
    k_gather<<<2048, 256, 0, stream>>>(epk2, rowse,
                                       (const uint4*)hb, (const float4*)b_gat,
                                       batch, pooled, N);
    k_fc<<<256, 256, 0, stream>>>(pooled, batch, N, W_fc, b_fc, out, G);
}

// Round 16
// 157.258 us; speedup vs baseline: 1.0662x; 1.0662x over previous
//
#include <hip/hip_runtime.h>
#include <math.h>

#define HIDDEN 64
#define TARGET 10
#define BKSH 9            // coarse bucket = 512 dst nodes
#define NBKMAX 256        // max coarse buckets (N <= 131072)

static __device__ __forceinline__ unsigned short f2bf(float f) {
    unsigned int u = __float_as_uint(f);
    u = (u + 0x7fffu + ((u >> 16) & 1u)) >> 16;   // RNE
    return (unsigned short)u;
}
static __device__ __forceinline__ float bf2f(unsigned short v) {
    return __uint_as_float((unsigned int)v << 16);
}

// ---------------------------------------------------------------------------
// K2: per-node, LDS-tiled register-blocked matmul (validated r2-r15).
//  x = relu(emb_act[act]+emb_loc[loc]); h = x @ W_gat (bf16 out)
//  a_src/a_dst folded in as reduction of the accumulator tile.
// ---------------------------------------------------------------------------
__global__ __launch_bounds__(256) void k_nodes(
        const int* __restrict__ act, const int* __restrict__ loc,
        const float* __restrict__ emb_act,
        const float* __restrict__ emb_loc,
        const float* __restrict__ W_gat,
        const float* __restrict__ att_src,
        const float* __restrict__ att_dst,
        unsigned short* __restrict__ hb,
        float* __restrict__ a_src, float* __restrict__ a_dst,
        int N) {
    __shared__ float xs[64][68];
    __shared__ float Wl[64][68];
    __shared__ int acts[64], locs[64];
    int tid = threadIdx.x;
    int base = blockIdx.x * 64;

    for (int i = tid; i < 4096; i += 256) Wl[i >> 6][i & 63] = W_gat[i];
    if (tid < 64) {
        int n = base + tid;
        acts[tid] = (n < N) ? act[n] : 0;
        locs[tid] = (n < N) ? loc[n] : 0;
    }
    __syncthreads();

    for (int i = tid; i < 1024; i += 256) {
        int r = i >> 4, k4 = i & 15;
        int n = base + r;
        float4 v = make_float4(0.f, 0.f, 0.f, 0.f);
        if (n < N) {
            float4 a = ((const float4*)emb_act)[acts[r] * 16 + k4];
            float4 b = ((const float4*)emb_loc)[locs[r] * 16 + k4];
            v.x = fmaxf(a.x + b.x, 0.f);
            v.y = fmaxf(a.y + b.y, 0.f);
            v.z = fmaxf(a.z + b.z, 0.f);
            v.w = fmaxf(a.w + b.w, 0.f);
        }
        *(float4*)&xs[r][k4 * 4] = v;
    }
    __syncthreads();

    int tx = tid & 15, ty = tid >> 4;
    float acc[4][4];
#pragma unroll
    for (int i = 0; i < 4; i++)
#pragma unroll
        for (int j = 0; j < 4; j++) acc[i][j] = 0.f;

#pragma unroll 4
    for (int k4 = 0; k4 < 16; k4++) {
        float4 xv[4], wv[4];
#pragma unroll
        for (int i = 0; i < 4; i++) xv[i] = *(const float4*)&xs[ty * 4 + i][k4 * 4];
#pragma unroll
        for (int kk = 0; kk < 4; kk++) wv[kk] = *(const float4*)&Wl[k4 * 4 + kk][tx * 4];
#pragma unroll
        for (int i = 0; i < 4; i++) {
            float xk0 = xv[i].x, xk1 = xv[i].y, xk2 = xv[i].z, xk3 = xv[i].w;
            acc[i][0] += xk0 * wv[0].x + xk1 * wv[1].x + xk2 * wv[2].x + xk3 * wv[3].x;
            acc[i][1] += xk0 * wv[0].y + xk1 * wv[1].y + xk2 * wv[2].y + xk3 * wv[3].y;
            acc[i][2] += xk0 * wv[0].z + xk1 * wv[1].z + xk2 * wv[2].z + xk3 * wv[3].z;
            acc[i][3] += xk0 * wv[0].w + xk1 * wv[1].w + xk2 * wv[2].w + xk3 * wv[3].w;
        }
    }

#pragma unroll
    for (int i = 0; i < 4; i++) {
        int n = base + ty * 4 + i;
        if (n < N) {
            ushort4 hv;
            hv.x = f2bf(acc[i][0]); hv.y = f2bf(acc[i][1]);
            hv.z = f2bf(acc[i][2]); hv.w = f2bf(acc[i][3]);
            *(ushort4*)&hb[(size_t)n * 64 + tx * 4] = hv;
        }
    }

    float4 as4 = ((const float4*)att_src)[tx];
    float4 ad4 = ((const float4*)att_dst)[tx];
    float ps[4], pd[4];
#pragma unroll
    for (int i = 0; i < 4; i++) {
        ps[i] = acc[i][0] * as4.x + acc[i][1] * as4.y + acc[i][2] * as4.z + acc[i][3] * as4.w;
        pd[i] = acc[i][0] * ad4.x + acc[i][1] * ad4.y + acc[i][2] * ad4.z + acc[i][3] * ad4.w;
    }
#pragma unroll
    for (int off = 1; off < 16; off <<= 1) {
#pragma unroll
        for (int i = 0; i < 4; i++) {
            ps[i] += __shfl_xor(ps[i], off, 64);
            pd[i] += __shfl_xor(pd[i], off, 64);
        }
    }
    if (tx == 0) {
#pragma unroll
        for (int i = 0; i < 4; i++) {
            int n = base + ty * 4 + i;
            if (n < N) { a_src[n] = ps[i]; a_dst[n] = pd[i]; }
        }
    }
}

// ---------------------------------------------------------------------------
// K3a: binned scatter pass A, fixed-capacity slabs, 4096 edges/block
// (validated r15). Inlined edge-table compute.
// Record: p.x = src | (d&511)<<20 ; p.y = exp(leaky_relu(alpha)) bits.
// ---------------------------------------------------------------------------
__global__ __launch_bounds__(256) void k_binA(
        const int* __restrict__ src, const int* __restrict__ dst,
        const int* __restrict__ travel,
        const float* __restrict__ dur,
        const float* __restrict__ tst,
        const float* __restrict__ tet,
        const float* __restrict__ a_src,
        const float* __restrict__ a_dst,
        const float* __restrict__ W_edge,
        const float* __restrict__ att_edge,
        const float* __restrict__ emb_travel,
        int* __restrict__ bcur,
        int2* __restrict__ epk, int E, int CAP) {
    __shared__ float we_s[67];
    __shared__ float ttbl[8];
    __shared__ float c012[3];
    __shared__ int cnt[NBKMAX];
    __shared__ int gb[NBKMAX];
    int tid = threadIdx.x;
    if (tid < 67) {
        float s = 0.f;
        for (int j = 0; j < 64; j++) s += W_edge[tid * 64 + j] * att_edge[j];
        we_s[tid] = s;
    }
    if (tid < NBKMAX) cnt[tid] = 0;
    __syncthreads();
    if (tid < 8) {
        float s = 0.f;
        for (int k = 0; k < 64; k++) s += emb_travel[tid * 64 + k] * we_s[k];
        ttbl[tid] = s;
    }
    if (tid == 64) { c012[0] = we_s[64]; c012[1] = we_s[65]; c012[2] = we_s[66]; }
    __syncthreads();
    float c0 = c012[0], c1 = c012[1], c2 = c012[2];

    int base = blockIdx.x * 4096 + tid;
    int rx[16], bks[16];
    float rv[16];
    bool ok[16];
#pragma unroll
    for (int j = 0; j < 16; j++) {
        int e = base + j * 256;
        ok[j] = e < E;
        if (ok[j]) {
            int s = src[e], d = dst[e];
            float al = a_src[s] + a_dst[d] + ttbl[travel[e]]
                     + c0 * dur[e] + c1 * tst[e] + c2 * tet[e];
            al = al > 0.f ? al : 0.2f * al;
            rv[j] = __expf(al);
            rx[j] = s | ((d & 511) << 20);
            bks[j] = d >> BKSH;
            atomicAdd(&cnt[bks[j]], 1);
        }
    }
    __syncthreads();
    if (tid < NBKMAX) {
        int c = cnt[tid];
        gb[tid] = c ? atomicAdd(&bcur[tid], c) : 0;
        cnt[tid] = 0;
    }
    __syncthreads();
#pragma unroll
    for (int j = 0; j < 16; j++) {
        if (ok[j]) {
            int slot = atomicAdd(&cnt[bks[j]], 1);
            int2 p;
            p.x = rx[j];
            p.y = __float_as_int(rv[j]);
            epk[(size_t)bks[j] * CAP + gb[bks[j]] + slot] = p;
        }
    }
}

// ---------------------------------------------------------------------------
// K3b: binned scatter pass B + LOCAL CSR (validated r13-r15). One block per
// 512-dst bucket: LDS hist -> wave-0 scan -> rowse[n]=(start,end) ->
// LDS-cursor sort into epk2 slab. All traffic L2-window-resident.
// ---------------------------------------------------------------------------
__global__ __launch_bounds__(256) void k_binB(
        const int2* __restrict__ epk,
        const int* __restrict__ bcur,
        int2* __restrict__ epk2,
        int2* __restrict__ rowse, int N, int CAP) {
    __shared__ int cnt[512];
    __shared__ int cur[512];
    int tid = threadIdx.x;
    int bk = blockIdx.x;
    int n0 = bk << BKSH;
    int cnt0 = bcur[bk];
    size_t base = (size_t)bk * CAP;

    for (int j = tid; j < 512; j += 256) cnt[j] = 0;
    __syncthreads();
    const int* epx = (const int*)epk;
    for (int i = tid; i < cnt0; i += 256)
        atomicAdd(&cnt[(epx[(base + i) * 2] >> 20) & 511], 1);
    __syncthreads();
    if (tid < 64) {
        int carry = 0;
#pragma unroll
        for (int c = 0; c < 8; c++) {
            int idx = c * 64 + tid;
            int v = cnt[idx];
            int s = v;
#pragma unroll
            for (int off = 1; off < 64; off <<= 1) {
                int t = __shfl_up(s, off, 64);
                if (tid >= off) s += t;
            }
            int excl = carry + s - v;
            cur[idx] = excl;
            int n = n0 + idx;
            if (n < N) rowse[n] = make_int2((int)base + excl, (int)base + excl + v);
            carry += __shfl(s, 63, 64);
        }
    }
    __syncthreads();
    for (int i = tid; i < cnt0; i += 256) {
        int2 p = epk[base + i];
        int dl = (p.x >> 20) & 511;
        int pos = atomicAdd(&cur[dl], 1);
        epk2[base + pos] = p;
    }
}

// ---------------------------------------------------------------------------
// K3f: atomic-free gather, contiguous node chunks per wave, in-register
// pooled accumulation with graph-boundary flush. REVERTED to the r14
// geometry: 8 edges in flight x 8 lanes x uint4 (VGPR 28, occupancy ~60%
// -- the r15 16-in-flight variant cost occupancy 61->41% and regressed).
// ---------------------------------------------------------------------------
__global__ __launch_bounds__(256) void k_gather(
        const int2* __restrict__ epk,
        const int2* __restrict__ rowse,
        const uint4* __restrict__ hbq,
        const float4* __restrict__ bg4,
        const int* __restrict__ batch,
        float* __restrict__ pooled_sums, int N) {
    int lane = threadIdx.x & 63;
    int wid = (blockIdx.x * blockDim.x + threadIdx.x) >> 6;
    int nw = (gridDim.x * blockDim.x) >> 6;
    int chunk = (N + nw - 1) / nw;
    int n0 = wid * chunk;
    if (n0 >= N) return;
    int n1 = n0 + chunk;
    if (n1 > N) n1 = N;
    int grp = lane >> 3;   // which of 8 edges in flight
    int sub = lane & 7;    // which 16B slice of the h row
    float4 b0 = bg4[sub * 2], b1 = bg4[sub * 2 + 1];
    int curg = -1;
    float p0 = 0.f, p1 = 0.f, p2 = 0.f, p3 = 0.f;
    float p4 = 0.f, p5 = 0.f, p6 = 0.f, p7 = 0.f;
    for (int n = n0; n < n1; n++) {
        int g = batch[n];
        if (g != curg) {
            if (curg >= 0 && grp == 0) {
                float* ps = &pooled_sums[(size_t)curg * 64 + sub * 8];
                unsafeAtomicAdd(ps + 0, p0);
                unsafeAtomicAdd(ps + 1, p1);
                unsafeAtomicAdd(ps + 2, p2);
                unsafeAtomicAdd(ps + 3, p3);
                unsafeAtomicAdd(ps + 4, p4);
                unsafeAtomicAdd(ps + 5, p5);
                unsafeAtomicAdd(ps + 6, p6);
                unsafeAtomicAdd(ps + 7, p7);
            }
            p0 = p1 = p2 = p3 = p4 = p5 = p6 = p7 = 0.f;
            curg = g;
        }
        int2 se = rowse[n];
        float a0 = 0.f, a1 = 0.f, a2 = 0.f, a3 = 0.f;
        float a4 = 0.f, a5 = 0.f, a6 = 0.f, a7 = 0.f, dv = 0.f;
        for (int e0 = se.x; e0 < se.y; e0 += 8) {
            int e = e0 + grp;
            if (e < se.y) {
                int2 p = epk[e];
                float ev = __int_as_float(p.y);
                int sidx = p.x & 0xFFFFF;
                uint4 hu = hbq[(size_t)sidx * 8 + sub];
                a0 += ev * bf2f((unsigned short)(hu.x));
                a1 += ev * bf2f((unsigned short)(hu.x >> 16));
                a2 += ev * bf2f((unsigned short)(hu.y));
                a3 += ev * bf2f((unsigned short)(hu.y >> 16));
                a4 += ev * bf2f((unsigned short)(hu.z));
                a5 += ev * bf2f((unsigned short)(hu.z >> 16));
                a6 += ev * bf2f((unsigned short)(hu.w));
                a7 += ev * bf2f((unsigned short)(hu.w >> 16));
                dv += ev;
            }
        }
#pragma unroll
        for (int off = 8; off < 64; off <<= 1) {
            a0 += __shfl_xor(a0, off, 64);
            a1 += __shfl_xor(a1, off, 64);
            a2 += __shfl_xor(a2, off, 64);
            a3 += __shfl_xor(a3, off, 64);
            a4 += __shfl_xor(a4, off, 64);
            a5 += __shfl_xor(a5, off, 64);
            a6 += __shfl_xor(a6, off, 64);
            a7 += __shfl_xor(a7, off, 64);
            dv += __shfl_xor(dv, off, 64);
        }
        float dn = dv > 1e-16f ? dv : 1e-16f;
        float inv = 1.f / dn;
        p0 += fmaxf(a0 * inv + b0.x, 0.f);
        p1 += fmaxf(a1 * inv + b0.y, 0.f);
        p2 += fmaxf(a2 * inv + b0.z, 0.f);
        p3 += fmaxf(a3 * inv + b0.w, 0.f);
        p4 += fmaxf(a4 * inv + b1.x, 0.f);
        p5 += fmaxf(a5 * inv + b1.y, 0.f);
        p6 += fmaxf(a6 * inv + b1.z, 0.f);
        p7 += fmaxf(a7 * inv + b1.w, 0.f);
    }
    if (curg >= 0 && grp == 0) {
        float* ps = &pooled_sums[(size_t)curg * 64 + sub * 8];
        unsafeAtomicAdd(ps + 0, p0);
        unsafeAtomicAdd(ps + 1, p1);
        unsafeAtomicAdd(ps + 2, p2);
        unsafeAtomicAdd(ps + 3, p3);
        unsafeAtomicAdd(ps + 4, p4);
        unsafeAtomicAdd(ps + 5, p5);
        unsafeAtomicAdd(ps + 6, p6);
        unsafeAtomicAdd(ps + 7, p7);
    }
}

// ---------------------------------------------------------------------------
// K5: pooled = sums/cnt; logits = pooled @ W_fc + b_fc ; out = log_softmax.
// ---------------------------------------------------------------------------
__global__ void k_fc(const float* __restrict__ pooled_sums,
                     const int* __restrict__ batch, int N,
                     const float* __restrict__ W_fc,
                     const float* __restrict__ b_fc,
                     float* __restrict__ out, int G) {
    int lane = threadIdx.x & 63;
    int wid = (blockIdx.x * blockDim.x + threadIdx.x) >> 6;
    int nw = (gridDim.x * blockDim.x) >> 6;
    for (int g = wid; g < G; g += nw) {
        int lo = 0, hi = N;
        while (lo < hi) { int mid = (lo + hi) >> 1; if (batch[mid] < g) lo = mid + 1; else hi = mid; }
        int start = lo;
        hi = N;
        while (lo < hi) { int mid = (lo + hi) >> 1; if (batch[mid] < g + 1) lo = mid + 1; else hi = mid; }
        float cnt = (float)(lo - start);
        float inv = 1.f / (cnt > 1.f ? cnt : 1.f);
        float p = pooled_sums[(size_t)g * 64 + lane] * inv;
        float logit[TARGET];
#pragma unroll
        for (int t = 0; t < TARGET; t++) {
            float v = p * W_fc[lane * TARGET + t];
#pragma unroll
            for (int o = 32; o > 0; o >>= 1) v += __shfl_xor(v, o, 64);
            logit[t] = v + b_fc[t];
        }
        float m = logit[0];
#pragma unroll
        for (int t = 1; t < TARGET; t++) m = fmaxf(m, logit[t]);
        float se = 0.f;
#pragma unroll
        for (int t = 0; t < TARGET; t++) se += expf(logit[t] - m);
        float lse = m + logf(se);
#pragma unroll
        for (int t = 0; t < TARGET; t++)
            if (lane == t) out[g * TARGET + t] = logit[t] - lse;
    }
}

extern "C" void kernel_launch(void* const* d_in, const int* in_sizes, int n_in,
                              void* d_out, int out_size, void* d_ws, size_t ws_size,
                              hipStream_t stream) {
    const int*   act        = (const int*)d_in[0];
    const int*   loc        = (const int*)d_in[1];
    const int*   travel     = (const int*)d_in[2];
    const float* dur        = (const float*)d_in[3];
    const float* tst        = (const float*)d_in[4];
    const float* tet        = (const float*)d_in[5];
    const int*   ei         = (const int*)d_in[6];
    const int*   batch      = (const int*)d_in[7];
    const float* emb_act    = (const float*)d_in[8];
    const float* emb_loc    = (const float*)d_in[9];
    const float* emb_travel = (const float*)d_in[10];
    const float* W_gat      = (const float*)d_in[11];
    const float* att_src    = (const float*)d_in[12];
    const float* att_dst    = (const float*)d_in[13];
    const float* W_edge     = (const float*)d_in[14];
    const float* att_edge   = (const float*)d_in[15];
    const float* b_gat      = (const float*)d_in[16];
    const float* W_fc       = (const float*)d_in[17];
    const float* b_fc       = (const float*)d_in[18];
    float* out = (float*)d_out;

    int N = in_sizes[0];
    int E = in_sizes[2];
    int G = out_size / TARGET;
    int NBK = (N + 511) >> BKSH;                       // 196 coarse buckets
    int CAP = (((E + NBK - 1) / NBK) + 4096 + 15) & ~15;  // slab capacity

    float* ws = (float*)d_ws;
    size_t off = 0;
    unsigned short* hb = (unsigned short*)(ws + off); off += (size_t)N * 32;  // bf16 h, 16B-aligned
    float* a_src    = ws + off; off += N;
    float* a_dst    = ws + off; off += N;
    int*   bcur     = (int*)(ws + off); off += NBKMAX;
    float* pooled   = ws + off; off += (size_t)G * 64;   // adjacent to bcur: one memset
    if (off & 1) off++;                   // 8B-align int2 arrays
    int2*  rowse    = (int2*)(ws + off); off += (size_t)N * 2;
    int2*  epk      = (int2*)(ws + off); off += (size_t)NBK * CAP * 2;
    int2*  epk2     = (int2*)(ws + off); off += (size_t)NBK * CAP * 2;

    hipMemsetAsync(bcur, 0, (NBKMAX + (size_t)G * 64) * sizeof(float), stream);

    k_nodes<<<(N + 63) / 64, 256, 0, stream>>>(act, loc, emb_act, emb_loc, W_gat,
                                               att_src, att_dst, hb, a_src, a_dst, N);
    k_binA<<<(E + 4095) / 4096, 256, 0, stream>>>(ei, ei + E, travel, dur, tst, tet,
                                                  a_src, a_dst, W_edge, att_edge,
                                                  emb_travel, bcur, epk, E, CAP);
    k_binB<<<NBK, 256, 0, stream>>>(epk, bcur, epk2, rowse, N, CAP);
    k_gather<<<2048, 256, 0, stream>>>(epk2, rowse,
                                       (const uint4*)hb, (const float4*)b_gat,
                                       batch, pooled, N);
    k_fc<<<256, 256, 0, stream>>>(pooled, batch, N, W_fc, b_fc, out, G);
}